// Round 6
// baseline (77.022 us; speedup 1.0000x reference)
//
#include <hip/hip_runtime.h>

// Upsample1d (linear kernel, reflect pad), stride-2 transposed depthwise FIR.
//   out[2m]   = 0.25*h[m-1] + 0.75*h[m]   (h[-1] := h[1])
//   out[2m+1] = 0.75*h[m]   + 0.25*h[m+1] (h[L]  := h[L-2])
// Taps hard-coded (absmax 0.0 verified).
//
// R5 structure (74.5 us, 5.4 TB/s): LDS-staged input, 1 contiguous f4 global
// load/thread, 2 lane-contiguous 1KB store instrs. This round: identical
// structure + NON-TEMPORAL load/store hints (`nt` flag) so the 268 MB output
// stream doesn't write-allocate in the 4 MiB/XCD L2 and evict the input
// stream — every byte here is touched exactly once, L2 gives zero reuse.

constexpr int L = 8192;

typedef float f32x4 __attribute__((ext_vector_type(4)));

__global__ __launch_bounds__(256) void upsample1d_kernel(
    const float* __restrict__ h, float* __restrict__ out) {
    __shared__ __align__(16) float lds[1026];   // 1024 main + 2 edge scalars

    const int t = threadIdx.x;
    const int fbase = blockIdx.x << 10;         // first input float of this block
    const float* __restrict__ hr = h + (size_t)blockIdx.y * L + fbase;

    // stage 4 KB of input (nt: no L2 allocation for the streamed input)
    reinterpret_cast<f32x4*>(lds)[t] =
        __builtin_nontemporal_load(reinterpret_cast<const f32x4*>(hr) + t);
    if (t == 0)   lds[1024] = (fbase > 0)        ? hr[-1]   : hr[1];     // h[-1]=h[1]
    if (t == 255) lds[1025] = (fbase + 1024 < L) ? hr[1024] : hr[1022];  // h[L]=h[L-2]
    __syncthreads();

    float* __restrict__ op = out + (size_t)blockIdx.y * 2 * L + 2 * fbase;

    // out tile A: local out-f4 index t (covers input floats 2t-1 .. 2t+2)
    {
        const float em1 = (t == 0) ? lds[1024] : lds[2 * t - 1];
        const float e0 = lds[2 * t], e1 = lds[2 * t + 1], e2 = lds[2 * t + 2];
        f32x4 a = {0.25f * em1 + 0.75f * e0,
                   0.75f * e0  + 0.25f * e1,
                   0.25f * e0  + 0.75f * e1,
                   0.75f * e1  + 0.25f * e2};
        __builtin_nontemporal_store(a, reinterpret_cast<f32x4*>(op) + t);
    }
    // out tile B: local out-f4 index 256+t (input floats 511+2t .. 514+2t)
    {
        const int base = 512 + 2 * t;
        const float em1 = lds[base - 1], e0 = lds[base], e1 = lds[base + 1];
        const float e2 = (t == 255) ? lds[1025] : lds[base + 2];
        f32x4 b = {0.25f * em1 + 0.75f * e0,
                   0.75f * e0  + 0.25f * e1,
                   0.25f * e0  + 0.75f * e1,
                   0.75f * e1  + 0.25f * e2};
        __builtin_nontemporal_store(b, reinterpret_cast<f32x4*>(op + 1024) + t);
    }
}

extern "C" void kernel_launch(void* const* d_in, const int* in_sizes, int n_in,
                              void* d_out, int out_size, void* d_ws, size_t ws_size,
                              hipStream_t stream) {
    const float* h = (const float*)d_in[0];
    float* out = (float*)d_out;

    const int nrows = in_sizes[0] / L;        // B*C = 4096
    dim3 grid((L / 4) / 256, nrows);          // (8, 4096)

    upsample1d_kernel<<<grid, 256, 0, stream>>>(h, out);
}

// Round 7
// 74.756 us; speedup vs baseline: 1.0303x; 1.0303x over previous
//
#include <hip/hip_runtime.h>

// Upsample1d (linear kernel, reflect pad), stride-2 transposed depthwise FIR.
//   out[2m]   = 0.25*h[m-1] + 0.75*h[m]   (h[-1] := h[1])
//   out[2m+1] = 0.75*h[m]   + 0.25*h[m+1] (h[L]  := h[L-2])
// Taps hard-coded (absmax 0.0 verified).
//
// R5 (74.5 us) minus the block barrier: each WAVE owns a self-contained
// 256-float input span staged into a wave-private LDS region (258 floats:
// 256 main + left/right edge scalars loaded by lanes 0/63). All ds_read
// dependencies are intra-wave, so no __syncthreads — just the compiler's
// lgkmcnt wait. Waves stream fully decoupled: the block's slowest load no
// longer gates every wave's stores. Loads: one coalesced f4/lane. Stores:
// two lane-contiguous 1 KB instrs per wave, identical addresses to R5.

constexpr int L = 8192;

__global__ __launch_bounds__(256) void upsample1d_kernel(
    const float* __restrict__ h, float* __restrict__ out) {
    __shared__ __align__(16) float lds[4 * 258];   // 4 waves x (256 main + 2 edges)

    const int t = threadIdx.x;
    const int w = t >> 6;                 // wave id in block
    const int l = t & 63;                 // lane id
    const int fbase = (blockIdx.x << 10) + (w << 8);  // wave's first input float
    const float* __restrict__ hr = h + (size_t)blockIdx.y * L + fbase;
    float* __restrict__ reg = lds + w * 258;          // wave-private LDS region

    // stage 1 KB (one f4 per lane, perfectly coalesced) + 2 edge scalars
    reinterpret_cast<float4*>(reg)[l] = reinterpret_cast<const float4*>(hr)[l];
    if (l == 0)  reg[256] = (fbase > 0)       ? hr[-1]  : hr[1];    // h[-1]=h[1]
    if (l == 63) reg[257] = (fbase + 256 < L) ? hr[256] : hr[254];  // h[L]=h[L-2]
    // no __syncthreads: all consumers are in this wave; lgkmcnt ordering suffices

    float* __restrict__ op = out + (size_t)blockIdx.y * 2 * L + 2 * (size_t)fbase;

    // out tile A: wave-local f4 index l (input floats 2l-1 .. 2l+2)
    {
        const float em1 = (l == 0) ? reg[256] : reg[2 * l - 1];
        const float e0 = reg[2 * l], e1 = reg[2 * l + 1], e2 = reg[2 * l + 2];
        float4 a;
        a.x = 0.25f * em1 + 0.75f * e0;
        a.y = 0.75f * e0  + 0.25f * e1;
        a.z = 0.25f * e0  + 0.75f * e1;
        a.w = 0.75f * e1  + 0.25f * e2;
        reinterpret_cast<float4*>(op)[l] = a;          // 1 KB lane-contiguous
    }
    // out tile B: wave-local f4 index 64+l (input floats 2l+127 .. 2l+130)
    {
        const float em1 = reg[2 * l + 127], e0 = reg[2 * l + 128], e1 = reg[2 * l + 129];
        const float e2 = (l == 63) ? reg[257] : reg[2 * l + 130];
        float4 b;
        b.x = 0.25f * em1 + 0.75f * e0;
        b.y = 0.75f * e0  + 0.25f * e1;
        b.z = 0.25f * e0  + 0.75f * e1;
        b.w = 0.75f * e1  + 0.25f * e2;
        reinterpret_cast<float4*>(op)[64 + l] = b;     // 1 KB lane-contiguous
    }
}

extern "C" void kernel_launch(void* const* d_in, const int* in_sizes, int n_in,
                              void* d_out, int out_size, void* d_ws, size_t ws_size,
                              hipStream_t stream) {
    const float* h = (const float*)d_in[0];
    float* out = (float*)d_out;

    const int nrows = in_sizes[0] / L;        // B*C = 4096
    dim3 grid((L / 4) / 256, nrows);          // (8, 4096) — same as R5

    upsample1d_kernel<<<grid, 256, 0, stream>>>(h, out);
}

// Round 8
// 61.592 us; speedup vs baseline: 1.2505x; 1.2137x over previous
//
#include <hip/hip_runtime.h>

// Upsample1d (linear kernel, reflect pad), stride-2 transposed depthwise FIR.
//   out[2m]   = 0.25*h[m-1] + 0.75*h[m]   (h[-1] := h[1])
//   out[2m+1] = 0.75*h[m]   + 0.25*h[m+1] (h[L]  := h[L-2])
// Taps hard-coded (absmax 0.0 verified).
//
// R5 structure (74.5 us best) + non-temporal STORES ONLY. R6 showed NT on
// both sides = -2.5 us, but load-NT is expected to HURT here (edge scalars
// hr[-1]/hr[1024] are neighbor-block lines -> L2 hits with normal loads,
// HBM misses with NT loads), while store-NT (no write-allocate for the
// 268 MB write-once output) is the part with upside. Clean A/B vs R5.

constexpr int L = 8192;

typedef float f32x4 __attribute__((ext_vector_type(4)));

__global__ __launch_bounds__(256) void upsample1d_kernel(
    const float* __restrict__ h, float* __restrict__ out) {
    __shared__ __align__(16) float lds[1026];   // 1024 main + 2 edge scalars

    const int t = threadIdx.x;
    const int fbase = blockIdx.x << 10;         // first input float of this block
    const float* __restrict__ hr = h + (size_t)blockIdx.y * L + fbase;

    // stage 4 KB of input (normal loads: edge scalars want L2 hits)
    reinterpret_cast<float4*>(lds)[t] = reinterpret_cast<const float4*>(hr)[t];
    if (t == 0)   lds[1024] = (fbase > 0)        ? hr[-1]   : hr[1];     // h[-1]=h[1]
    if (t == 255) lds[1025] = (fbase + 1024 < L) ? hr[1024] : hr[1022];  // h[L]=h[L-2]
    __syncthreads();

    float* __restrict__ op = out + (size_t)blockIdx.y * 2 * L + 2 * fbase;

    // out tile A: local out-f4 index t (covers input floats 2t-1 .. 2t+2)
    {
        const float em1 = (t == 0) ? lds[1024] : lds[2 * t - 1];
        const float e0 = lds[2 * t], e1 = lds[2 * t + 1], e2 = lds[2 * t + 2];
        f32x4 a = {0.25f * em1 + 0.75f * e0,
                   0.75f * e0  + 0.25f * e1,
                   0.25f * e0  + 0.75f * e1,
                   0.75f * e1  + 0.25f * e2};
        __builtin_nontemporal_store(a, reinterpret_cast<f32x4*>(op) + t);
    }
    // out tile B: local out-f4 index 256+t (input floats 511+2t .. 514+2t)
    {
        const int base = 512 + 2 * t;
        const float em1 = lds[base - 1], e0 = lds[base], e1 = lds[base + 1];
        const float e2 = (t == 255) ? lds[1025] : lds[base + 2];
        f32x4 b = {0.25f * em1 + 0.75f * e0,
                   0.75f * e0  + 0.25f * e1,
                   0.25f * e0  + 0.75f * e1,
                   0.75f * e1  + 0.25f * e2};
        __builtin_nontemporal_store(b, reinterpret_cast<f32x4*>(op + 1024) + t);
    }
}

extern "C" void kernel_launch(void* const* d_in, const int* in_sizes, int n_in,
                              void* d_out, int out_size, void* d_ws, size_t ws_size,
                              hipStream_t stream) {
    const float* h = (const float*)d_in[0];
    float* out = (float*)d_out;

    const int nrows = in_sizes[0] / L;        // B*C = 4096
    dim3 grid((L / 4) / 256, nrows);          // (8, 4096)

    upsample1d_kernel<<<grid, 256, 0, stream>>>(h, out);
}